// Round 13
// baseline (42.203 us; speedup 1.0000x reference)
//
#include <hip/hip_runtime.h>
#include <stdint.h>

// ANFM: B=4096, F=26, V=20000, E=64, P=325 pairs.
// k1: 8 samples/block (512 thr), ONE WAVE PER SAMPLE, single barrier.
//     Phase-2 body is BYTE-IDENTICAL to the round-9 known-good codegen
//     (fused MFMA->exp->online acc, unroll 1). Changes vs round 12:
//     - 8 samples/block at launch_bounds(512,2): VGPR cap 256 (UP from 128,
//       spill-safe direction), LDS ~40KB -> 2 blocks/CU = 16 waves/CU,
//       per-block fixed cost (W^T/pij/ap/ab staging) amortized over 8.
//     - issue-early gather: wave loads own x_idx row + embed float4s +
//       lr scalar BEFORE cooperative staging (HBM latency hidden); lr and
//       idx register-resident (sIdx/lrbuf LDS deleted).
// k2: round-12 MFMA MLP head, unchanged (validated, ~5us).
#define B_N 4096
#define F_N 26
#define V_N 20000
#define E_N 64
#define P_N 325
#define PT  21   // ceil(336/16) pair M-tiles (padded to 336 rows)
#define SPB 8    // samples per attn block

typedef __attribute__((ext_vector_type(8))) _Float16 half8;
typedef __attribute__((ext_vector_type(4))) _Float16 half4;
typedef __attribute__((ext_vector_type(4))) float floatx4;

// ---------------- attention kernel: 8 samples/block, 1 wave/sample --------
__global__ __launch_bounds__(512, 2) void anfm_attn_kernel(
    const int* __restrict__ x_idx, const float* __restrict__ embed_w,
    const float* __restrict__ embed_b, const float* __restrict__ att_w,
    const float* __restrict__ att_b, const float* __restrict__ att_p,
    float* __restrict__ ws_afm, float* __restrict__ ws_lr)
{
    __shared__ _Float16 xwb[SPB][F_N][72];  // fp16 gathered embeds (pad 72)
    __shared__ _Float16 WT[64][72];         // W^T fp16: WT[col][k] (pad 72)
    __shared__ unsigned short pijL[336];    // (i<<8)|j per pair
    __shared__ float apL[64], abL[64];      // attention_p / attention_b

    const int tid  = threadIdx.x;
    const int lane = tid & 63;
    const int wid  = tid >> 6;               // 0..7
    const int c16  = lane & 15;
    const int g    = lane >> 4;
    const int b    = blockIdx.x * SPB + wid; // sample owned by this wave

    // ---- phase A (wave-local, ISSUE EARLY): idx row, lr, embed gathers ----
    int myidx = (lane < F_N) ? x_idx[b * F_N + lane] : 0;
    float lv  = (lane < F_N) ? embed_b[lane * V_N + myidx] : 0.f;  // lr term
    float4 gv[7];
    #pragma unroll
    for (int it = 0; it < 7; it++) {
        int f = it * 4 + g;
        int fc = (f < F_N) ? f : 0;
        int idxf = __shfl(myidx, fc);
        const float4* src = reinterpret_cast<const float4*>(
            embed_w + ((size_t)(fc * V_N + idxf)) * E_N);
        gv[it] = src[c16];                   // in flight under staging below
    }

    // ---- phase B (cooperative): pair map, ap/ab, W^T staging ----
    if (tid < 336) {
        int p = tid;
        int i = 0, j = 1;
        if (p < P_N) {
            i = (int)((51.0f - sqrtf(2601.0f - 8.0f * (float)p)) * 0.5f);
            if (i * (51 - i) / 2 > p) i--;
            else if ((i + 1) * (50 - i) / 2 <= p) i++;
            j = p - i * (51 - i) / 2 + i + 1;
        }
        pijL[p] = (unsigned short)((i << 8) | j);
    } else if (tid < 400) {
        apL[tid - 336] = att_p[tid - 336];
    } else if (tid < 464) {
        abL[tid - 400] = att_b[tid - 400];
    }
    // W^T staging: WT[col][k] = att_w[k][col]  (coalesced f32 read)
    for (int idx = tid; idx < 64 * 64; idx += 512) {
        int k = idx >> 6, col = idx & 63;
        WT[col][k] = (_Float16)att_w[idx];
    }

    // ---- write gathered embeds to own xwb slice (wave-local) ----
    #pragma unroll
    for (int it = 0; it < 7; it++) {
        int f = it * 4 + g;
        if (f < F_N) {
            float4 v = gv[it];
            half4 hv = {(_Float16)v.x, (_Float16)v.y, (_Float16)v.z, (_Float16)v.w};
            *reinterpret_cast<half4*>(&xwb[wid][f][c16 * 4]) = hv;
        }
    }
    __syncthreads();   // the ONLY block-wide barrier

    // W fragments (rows of W^T) in registers; k-slot (g,u) <-> k = s*32+8g+u
    half8 bfr[4][2];
    #pragma unroll
    for (int nt = 0; nt < 4; nt++)
        #pragma unroll
        for (int s = 0; s < 2; s++)
            bfr[nt][s] = *reinterpret_cast<const half8*>(
                &WT[nt * 16 + c16][s * 32 + g * 8]);

    // ---- phase 2 (wave-local, FUSED): MFMA scores -> exp -> weighted acc ----
    // D = W^T(A) @ pairs^T(B): D col = lane&15 = pair, row = g*4+r = hidden n.
    // After the cross-g shuffles every lane holds the FULL score of pair c16
    // in this tile -> per-lane w = exp(score) weights the af fragments this
    // lane already owns (e = s*32 + 8g + u). Max-free exp: softmax is
    // shift-invariant and scores are O(0.1) -> no overflow.
    float acf[16];
    #pragma unroll
    for (int u = 0; u < 16; u++) acf[u] = 0.f;
    float Zp = 0.f;

    #pragma unroll 1
    for (int t = 0; t < PT; t++) {
        int pk = pijL[t * 16 + c16];
        int ri = pk >> 8, rj = pk & 255;
        half8 af[2];
        #pragma unroll
        for (int s = 0; s < 2; s++) {
            half8 xv = *reinterpret_cast<const half8*>(&xwb[wid][ri][s * 32 + g * 8]);
            half8 yv = *reinterpret_cast<const half8*>(&xwb[wid][rj][s * 32 + g * 8]);
            af[s] = xv * yv;   // 4x v_pk_mul_f16
        }
        float scq = 0.f;
        #pragma unroll
        for (int nt = 0; nt < 4; nt++) {
            floatx4 acc = *reinterpret_cast<const floatx4*>(&abL[nt * 16 + g * 4]);
            acc = __builtin_amdgcn_mfma_f32_16x16x32_f16(bfr[nt][0], af[0], acc, 0, 0, 0);
            acc = __builtin_amdgcn_mfma_f32_16x16x32_f16(bfr[nt][1], af[1], acc, 0, 0, 0);
            floatx4 ap4 = *reinterpret_cast<const floatx4*>(&apL[nt * 16 + g * 4]);
            #pragma unroll
            for (int r = 0; r < 4; r++)
                scq = fmaf(ap4[r], fmaxf(acc[r], 0.f), scq);
        }
        scq += __shfl_xor(scq, 16);   // reduce over g groups (hidden chunks)
        scq += __shfl_xor(scq, 32);
        float w = (t * 16 + c16 < P_N) ? __expf(scq) : 0.f;
        Zp += w;
        #pragma unroll
        for (int s = 0; s < 2; s++)
            #pragma unroll
            for (int u = 0; u < 8; u++)
                acf[s * 8 + u] = fmaf((float)af[s][u], w, acf[s * 8 + u]);  // fma_mix
    }

    // ---- reduce over the 16 pair-columns (c16) within each g-group ----
    #pragma unroll
    for (int msk = 1; msk <= 8; msk <<= 1) {
        Zp += __shfl_xor(Zp, msk);
        #pragma unroll
        for (int u = 0; u < 16; u++) acf[u] += __shfl_xor(acf[u], msk);
    }

    // ---- write afm (lanes c16==0: g picks the 8-element e-chunks) + lr ----
    if (c16 == 0) {
        float rZ = 1.f / Zp;
        #pragma unroll
        for (int s = 0; s < 2; s++) {
            floatx4 o0 = {acf[s * 8 + 0] * rZ, acf[s * 8 + 1] * rZ,
                          acf[s * 8 + 2] * rZ, acf[s * 8 + 3] * rZ};
            floatx4 o1 = {acf[s * 8 + 4] * rZ, acf[s * 8 + 5] * rZ,
                          acf[s * 8 + 6] * rZ, acf[s * 8 + 7] * rZ};
            *reinterpret_cast<floatx4*>(&ws_afm[(size_t)b * 64 + s * 32 + g * 8])     = o0;
            *reinterpret_cast<floatx4*>(&ws_afm[(size_t)b * 64 + s * 32 + g * 8 + 4]) = o1;
        }
    }
    #pragma unroll
    for (int off = 32; off; off >>= 1) lv += __shfl_xor(lv, off);
    if (lane == 0) ws_lr[b] = lv;
}

// ---------------- MFMA MLP head: 16 samples per block (one M-tile) -------
// Same verified MFMA convention as attn: mfma(A,B) -> D row = A-lane index
// (g*4+r), D col = B-lane index (c16); k-slot (g,u) <-> k = base + 8g + u,
// identical for A and B fragments.
__global__ __launch_bounds__(256, 4) void anfm_mlp_kernel(
    const float* __restrict__ ws_afm, const float* __restrict__ ws_lr,
    const float* __restrict__ w0, const float* __restrict__ b0,
    const float* __restrict__ w1, const float* __restrict__ b1,
    const float* __restrict__ w2, const float* __restrict__ b2,
    const float* __restrict__ bias, float* __restrict__ out)
{
    __shared__ _Float16 afmL[16][72];    // A for L0 (fp16, pad 72)
    __shared__ _Float16 h0L[16][264];    // relu(L0) fp16, K=256 (pad 264)
    __shared__ float    h1L[16][132];    // relu-input of L2 (f32, pad 132)

    const int tid  = threadIdx.x;
    const int lane = tid & 63;
    const int wid  = tid >> 6;
    const int c16  = lane & 15;
    const int g    = lane >> 4;
    const int blk  = blockIdx.x;

    // stage afm -> fp16 LDS (A rows = samples)
    for (int it = tid; it < 16 * 64; it += 256) {
        int s = it >> 6, e = it & 63;
        afmL[s][e] = (_Float16)ws_afm[((size_t)blk * 16 + s) * 64 + e];
    }
    __syncthreads();

    // ---- L0: D[16,256] = afm[16,64] @ w0[64,256] + b0, relu -> h0L ----
    {
        half8 af[2];
        #pragma unroll
        for (int s = 0; s < 2; s++)
            af[s] = *reinterpret_cast<const half8*>(&afmL[c16][s * 32 + g * 8]);
        #pragma unroll
        for (int q = 0; q < 4; q++) {
            int n = (wid * 4 + q) * 16 + c16;
            half8 bf[2];
            #pragma unroll
            for (int s = 0; s < 2; s++)
                #pragma unroll
                for (int u = 0; u < 8; u++)
                    bf[s][u] = (_Float16)w0[(s * 32 + g * 8 + u) * 256 + n];
            floatx4 acc = {0.f, 0.f, 0.f, 0.f};
            acc = __builtin_amdgcn_mfma_f32_16x16x32_f16(af[0], bf[0], acc, 0, 0, 0);
            acc = __builtin_amdgcn_mfma_f32_16x16x32_f16(af[1], bf[1], acc, 0, 0, 0);
            float b0n = b0[n];
            #pragma unroll
            for (int r = 0; r < 4; r++)
                h0L[g * 4 + r][n] = (_Float16)fmaxf(acc[r] + b0n, 0.f);
        }
    }
    __syncthreads();

    // ---- L1: D[16,128] = h0[16,256] @ w1[256,128] + b1, relu -> h1L ----
    #pragma unroll
    for (int q = 0; q < 2; q++) {
        int n = (wid * 2 + q) * 16 + c16;
        floatx4 acc = {0.f, 0.f, 0.f, 0.f};
        #pragma unroll
        for (int ks = 0; ks < 8; ks++) {
            half8 af = *reinterpret_cast<const half8*>(&h0L[c16][ks * 32 + g * 8]);
            half8 bf;
            #pragma unroll
            for (int u = 0; u < 8; u++)
                bf[u] = (_Float16)w1[(ks * 32 + g * 8 + u) * 128 + n];
            acc = __builtin_amdgcn_mfma_f32_16x16x32_f16(af, bf, acc, 0, 0, 0);
        }
        float b1n = b1[n];
        #pragma unroll
        for (int r = 0; r < 4; r++)
            h1L[g * 4 + r][n] = fmaxf(acc[r] + b1n, 0.f);
    }
    __syncthreads();

    // ---- L2: out = h1 @ w2 + b2 + bias + lr ----
    float w2a = w2[lane * 2], w2b = w2[lane * 2 + 1];
    float base = b2[0] + bias[0];
    #pragma unroll
    for (int s = 0; s < 4; s++) {
        int m = wid * 4 + s;
        float part = fmaf(h1L[m][lane * 2], w2a, h1L[m][lane * 2 + 1] * w2b);
        #pragma unroll
        for (int off = 32; off; off >>= 1) part += __shfl_xor(part, off);
        if (lane == 0) {
            int sg = blk * 16 + m;
            out[sg] = part + base + ws_lr[sg];
        }
    }
}

extern "C" void kernel_launch(void* const* d_in, const int* in_sizes, int n_in,
                              void* d_out, int out_size, void* d_ws, size_t ws_size,
                              hipStream_t stream) {
    const int*   x_idx   = (const int*)d_in[0];
    const float* embed_w = (const float*)d_in[1];
    const float* embed_b = (const float*)d_in[2];
    const float* att_w   = (const float*)d_in[3];
    const float* att_b   = (const float*)d_in[4];
    const float* att_p   = (const float*)d_in[5];
    const float* w0      = (const float*)d_in[6];
    const float* b0      = (const float*)d_in[7];
    const float* w1      = (const float*)d_in[8];
    const float* b1      = (const float*)d_in[9];
    const float* w2      = (const float*)d_in[10];
    const float* b2      = (const float*)d_in[11];
    const float* bias    = (const float*)d_in[12];

    // ws layout: afm [B,64] f32 | lr [B] f32
    float* ws_afm = (float*)d_ws;
    float* ws_lr  = ws_afm + (size_t)B_N * E_N;
    float* out    = (float*)d_out;

    anfm_attn_kernel<<<B_N / SPB, 512, 0, stream>>>(x_idx, embed_w, embed_b,
                                                    att_w, att_b, att_p,
                                                    ws_afm, ws_lr);
    anfm_mlp_kernel<<<B_N / 16, 256, 0, stream>>>(ws_afm, ws_lr,
                                                  w0, b0, w1, b1, w2, b2, bias, out);
}

// Round 14
// 34.275 us; speedup vs baseline: 1.2313x; 1.2313x over previous
//
#include <hip/hip_runtime.h>
#include <stdint.h>

// ANFM: B=4096, F=26, V=20000, E=64, P=325 pairs.
// SINGLE FUSED KERNEL: 8 samples/block (512 thr), 1 wave/sample for the
// attention phase (byte-identical r13/r9 fused MFMA->exp->online-acc body,
// the only clean codegen point; unroll 1, VGPR cap 128). afm/lr land in
// LDS; then an in-block MFMA MLP phase (r12's verified head, re-indexed
// for 8 waves, M-tile rows 8-15 dead) writes out directly.
// Kills: mlp launch+gap, 1MB afm ws round-trip, mlp afm re-staging.
#define B_N 4096
#define F_N 26
#define V_N 20000
#define E_N 64
#define P_N 325
#define PT  21   // ceil(336/16) pair M-tiles (padded to 336 rows)
#define SPB 8    // samples per block

typedef __attribute__((ext_vector_type(8))) _Float16 half8;
typedef __attribute__((ext_vector_type(4))) _Float16 half4;
typedef __attribute__((ext_vector_type(4))) float floatx4;

__global__ __launch_bounds__(512, 4) void anfm_fused_kernel(
    const int* __restrict__ x_idx, const float* __restrict__ embed_w,
    const float* __restrict__ embed_b, const float* __restrict__ att_w,
    const float* __restrict__ att_b, const float* __restrict__ att_p,
    const float* __restrict__ w0, const float* __restrict__ b0,
    const float* __restrict__ w1, const float* __restrict__ b1,
    const float* __restrict__ w2, const float* __restrict__ b2,
    const float* __restrict__ bias, float* __restrict__ out)
{
    __shared__ _Float16 xwb[SPB][F_N][72];  // fp16 gathered embeds (pad 72)
    __shared__ _Float16 WT[64][72];         // W^T fp16: WT[col][k] (pad 72)
    __shared__ unsigned short pijL[336];    // (i<<8)|j per pair
    __shared__ float apL[64], abL[64];      // attention_p / attention_b
    __shared__ _Float16 afmL[16][72];       // afm fp16 (rows 8-15 zero)
    __shared__ _Float16 h0L[16][264];       // relu(L0) fp16 (rows 8-15 dead)
    __shared__ float    h1L[16][132];       // relu(L1) f32  (rows 8-15 dead)
    __shared__ float    lrL[SPB];

    const int tid  = threadIdx.x;
    const int lane = tid & 63;
    const int wid  = tid >> 6;               // 0..7
    const int c16  = lane & 15;
    const int g    = lane >> 4;
    const int b    = blockIdx.x * SPB + wid; // sample owned by this wave

    // ---- phase A (wave-local, ISSUE EARLY): idx row, lr, embed gathers ----
    int myidx = (lane < F_N) ? x_idx[b * F_N + lane] : 0;
    float lv  = (lane < F_N) ? embed_b[lane * V_N + myidx] : 0.f;  // lr term
    float4 gv[7];
    #pragma unroll
    for (int it = 0; it < 7; it++) {
        int f = it * 4 + g;
        int fc = (f < F_N) ? f : 0;
        int idxf = __shfl(myidx, fc);
        const float4* src = reinterpret_cast<const float4*>(
            embed_w + ((size_t)(fc * V_N + idxf)) * E_N);
        gv[it] = src[c16];                   // in flight under staging below
    }

    // ---- phase B (cooperative): pair map, ap/ab, W^T staging, afm zero ----
    if (tid < 336) {
        int p = tid;
        int i = 0, j = 1;
        if (p < P_N) {
            i = (int)((51.0f - sqrtf(2601.0f - 8.0f * (float)p)) * 0.5f);
            if (i * (51 - i) / 2 > p) i--;
            else if ((i + 1) * (50 - i) / 2 <= p) i++;
            j = p - i * (51 - i) / 2 + i + 1;
        }
        pijL[p] = (unsigned short)((i << 8) | j);
    } else if (tid < 400) {
        apL[tid - 336] = att_p[tid - 336];
    } else if (tid < 464) {
        abL[tid - 400] = att_b[tid - 400];
    }
    // zero dead rows 8..15 of afmL (576 halves)
    for (int z = tid; z < 576; z += 512) {
        int r = z / 72, c = z - r * 72;
        afmL[8 + r][c] = (_Float16)0.f;
    }
    // W^T staging: WT[col][k] = att_w[k][col]  (coalesced f32 read)
    for (int idx = tid; idx < 64 * 64; idx += 512) {
        int k = idx >> 6, col = idx & 63;
        WT[col][k] = (_Float16)att_w[idx];
    }

    // ---- write gathered embeds to own xwb slice (wave-local) ----
    #pragma unroll
    for (int it = 0; it < 7; it++) {
        int f = it * 4 + g;
        if (f < F_N) {
            float4 v = gv[it];
            half4 hv = {(_Float16)v.x, (_Float16)v.y, (_Float16)v.z, (_Float16)v.w};
            *reinterpret_cast<half4*>(&xwb[wid][f][c16 * 4]) = hv;
        }
    }
    __syncthreads();

    // W fragments (rows of W^T) in registers; k-slot (g,u) <-> k = s*32+8g+u
    half8 bfr[4][2];
    #pragma unroll
    for (int nt = 0; nt < 4; nt++)
        #pragma unroll
        for (int s = 0; s < 2; s++)
            bfr[nt][s] = *reinterpret_cast<const half8*>(
                &WT[nt * 16 + c16][s * 32 + g * 8]);

    // ---- phase 2 (wave-local, FUSED): MFMA scores -> exp -> weighted acc ----
    // D = W^T(A) @ pairs^T(B): D col = lane&15 = pair, row = g*4+r = hidden n.
    // After the cross-g shuffles every lane holds the FULL score of pair c16
    // in this tile -> per-lane w = exp(score) weights the af fragments this
    // lane already owns (e = s*32 + 8g + u). Max-free exp: softmax is
    // shift-invariant and scores are O(0.1) -> no overflow.
    float acf[16];
    #pragma unroll
    for (int u = 0; u < 16; u++) acf[u] = 0.f;
    float Zp = 0.f;

    #pragma unroll 1
    for (int t = 0; t < PT; t++) {
        int pk = pijL[t * 16 + c16];
        int ri = pk >> 8, rj = pk & 255;
        half8 af[2];
        #pragma unroll
        for (int s = 0; s < 2; s++) {
            half8 xv = *reinterpret_cast<const half8*>(&xwb[wid][ri][s * 32 + g * 8]);
            half8 yv = *reinterpret_cast<const half8*>(&xwb[wid][rj][s * 32 + g * 8]);
            af[s] = xv * yv;   // 4x v_pk_mul_f16
        }
        float scq = 0.f;
        #pragma unroll
        for (int nt = 0; nt < 4; nt++) {
            floatx4 acc = *reinterpret_cast<const floatx4*>(&abL[nt * 16 + g * 4]);
            acc = __builtin_amdgcn_mfma_f32_16x16x32_f16(bfr[nt][0], af[0], acc, 0, 0, 0);
            acc = __builtin_amdgcn_mfma_f32_16x16x32_f16(bfr[nt][1], af[1], acc, 0, 0, 0);
            floatx4 ap4 = *reinterpret_cast<const floatx4*>(&apL[nt * 16 + g * 4]);
            #pragma unroll
            for (int r = 0; r < 4; r++)
                scq = fmaf(ap4[r], fmaxf(acc[r], 0.f), scq);
        }
        scq += __shfl_xor(scq, 16);   // reduce over g groups (hidden chunks)
        scq += __shfl_xor(scq, 32);
        float w = (t * 16 + c16 < P_N) ? __expf(scq) : 0.f;
        Zp += w;
        #pragma unroll
        for (int s = 0; s < 2; s++)
            #pragma unroll
            for (int u = 0; u < 8; u++)
                acf[s * 8 + u] = fmaf((float)af[s][u], w, acf[s * 8 + u]);  // fma_mix
    }

    // ---- reduce over the 16 pair-columns (c16) within each g-group ----
    #pragma unroll
    for (int msk = 1; msk <= 8; msk <<= 1) {
        Zp += __shfl_xor(Zp, msk);
        #pragma unroll
        for (int u = 0; u < 16; u++) acf[u] += __shfl_xor(acf[u], msk);
    }

    // ---- write afm (fp16) + lr to LDS for the MLP phase ----
    if (c16 == 0) {
        float rZ = 1.f / Zp;
        #pragma unroll
        for (int s = 0; s < 2; s++) {
            half4 o0 = {(_Float16)(acf[s * 8 + 0] * rZ), (_Float16)(acf[s * 8 + 1] * rZ),
                        (_Float16)(acf[s * 8 + 2] * rZ), (_Float16)(acf[s * 8 + 3] * rZ)};
            half4 o1 = {(_Float16)(acf[s * 8 + 4] * rZ), (_Float16)(acf[s * 8 + 5] * rZ),
                        (_Float16)(acf[s * 8 + 6] * rZ), (_Float16)(acf[s * 8 + 7] * rZ)};
            *reinterpret_cast<half4*>(&afmL[wid][s * 32 + g * 8])     = o0;
            *reinterpret_cast<half4*>(&afmL[wid][s * 32 + g * 8 + 4]) = o1;
        }
    }
    #pragma unroll
    for (int off = 32; off; off >>= 1) lv += __shfl_xor(lv, off);
    if (lane == 0) lrL[wid] = lv;
    __syncthreads();

    // ================= MLP phase (in-block, r12-verified head) =============
    // mfma(A,B): D row = g*4+r (= A row index), D col = c16 (= B n index);
    // k-slot (g,u) <-> k = base + 8g + u, identical A and B.
    // Only D rows < 8 are real samples; rows 8-15 dead (afmL zeroed).

    // ---- L0: D[16,256] = afm @ w0 + b0, relu -> h0L. 16 n-tiles / 8 waves.
    {
        half8 af0[2];
        #pragma unroll
        for (int s = 0; s < 2; s++)
            af0[s] = *reinterpret_cast<const half8*>(&afmL[c16][s * 32 + g * 8]);
        #pragma unroll
        for (int q = 0; q < 2; q++) {
            int n = (wid * 2 + q) * 16 + c16;
            half8 bf[2];
            #pragma unroll
            for (int s = 0; s < 2; s++)
                #pragma unroll
                for (int u = 0; u < 8; u++)
                    bf[s][u] = (_Float16)w0[(s * 32 + g * 8 + u) * 256 + n];
            floatx4 acc = {0.f, 0.f, 0.f, 0.f};
            acc = __builtin_amdgcn_mfma_f32_16x16x32_f16(af0[0], bf[0], acc, 0, 0, 0);
            acc = __builtin_amdgcn_mfma_f32_16x16x32_f16(af0[1], bf[1], acc, 0, 0, 0);
            float b0n = b0[n];
            #pragma unroll
            for (int r = 0; r < 4; r++)
                h0L[g * 4 + r][n] = (_Float16)fmaxf(acc[r] + b0n, 0.f);
        }
    }
    __syncthreads();

    // ---- L1: D[16,128] = h0 @ w1 + b1, relu -> h1L. 8 n-tiles / 8 waves.
    {
        int n = wid * 16 + c16;
        floatx4 acc = {0.f, 0.f, 0.f, 0.f};
        #pragma unroll
        for (int ks = 0; ks < 8; ks++) {
            half8 af1 = *reinterpret_cast<const half8*>(&h0L[c16][ks * 32 + g * 8]);
            half8 bf;
            #pragma unroll
            for (int u = 0; u < 8; u++)
                bf[u] = (_Float16)w1[(ks * 32 + g * 8 + u) * 128 + n];
            acc = __builtin_amdgcn_mfma_f32_16x16x32_f16(af1, bf, acc, 0, 0, 0);
        }
        float b1n = b1[n];
        #pragma unroll
        for (int r = 0; r < 4; r++)
            h1L[g * 4 + r][n] = fmaxf(acc[r] + b1n, 0.f);
    }
    __syncthreads();

    // ---- L2: out = h1 @ w2 + b2 + bias + lr. Wave wid -> sample wid. ----
    {
        float part = fmaf(h1L[wid][lane * 2], w2[lane * 2],
                          h1L[wid][lane * 2 + 1] * w2[lane * 2 + 1]);
        #pragma unroll
        for (int off = 32; off; off >>= 1) part += __shfl_xor(part, off);
        if (lane == 0)
            out[blockIdx.x * SPB + wid] = part + b2[0] + bias[0] + lrL[wid];
    }
}

extern "C" void kernel_launch(void* const* d_in, const int* in_sizes, int n_in,
                              void* d_out, int out_size, void* d_ws, size_t ws_size,
                              hipStream_t stream) {
    const int*   x_idx   = (const int*)d_in[0];
    const float* embed_w = (const float*)d_in[1];
    const float* embed_b = (const float*)d_in[2];
    const float* att_w   = (const float*)d_in[3];
    const float* att_b   = (const float*)d_in[4];
    const float* att_p   = (const float*)d_in[5];
    const float* w0      = (const float*)d_in[6];
    const float* b0      = (const float*)d_in[7];
    const float* w1      = (const float*)d_in[8];
    const float* b1      = (const float*)d_in[9];
    const float* w2      = (const float*)d_in[10];
    const float* b2      = (const float*)d_in[11];
    const float* bias    = (const float*)d_in[12];
    float*       out     = (float*)d_out;

    anfm_fused_kernel<<<B_N / SPB, 512, 0, stream>>>(
        x_idx, embed_w, embed_b, att_w, att_b, att_p,
        w0, b0, w1, b1, w2, b2, bias, out);
}